// Round 1
// baseline (6901.454 us; speedup 1.0000x reference)
//
#include <hip/hip_runtime.h>
#include <math.h>

#define NX 2048
#define LY 256
#define NH 24
#define DH 128
#define DXC 3072
#define DYC 1536
#define NLTOK 2304
#define NTOT 2248
#define RMS_EPS 1e-6f

// ---------------- rmsnorm * (1 + scale) ----------------
__global__ __launch_bounds__(256) void rmsnorm_scale_kernel(
    const float* __restrict__ in, const float* __restrict__ scale,
    float* __restrict__ out, int cols)
{
    const int row = blockIdx.x;
    const int tid = threadIdx.x;
    const float* rp = in + (size_t)row * cols;
    const int nv = cols >> 2;
    float4 vals[3];
    float ss = 0.f;
    int cnt = 0;
    for (int c4 = tid; c4 < nv; c4 += 256) {
        float4 v = ((const float4*)rp)[c4];
        vals[cnt++] = v;
        ss += v.x * v.x + v.y * v.y + v.z * v.z + v.w * v.w;
    }
#pragma unroll
    for (int m = 1; m < 64; m <<= 1) ss += __shfl_xor(ss, m, 64);
    __shared__ float red[4];
    if ((tid & 63) == 0) red[tid >> 6] = ss;
    __syncthreads();
    const float tot = red[0] + red[1] + red[2] + red[3];
    const float r = rsqrtf(tot / (float)cols + RMS_EPS);
    float* op = out + (size_t)row * cols;
    cnt = 0;
    for (int c4 = tid; c4 < nv; c4 += 256) {
        float4 v = vals[cnt++];
        float4 s = ((const float4*)scale)[c4];
        float4 o;
        o.x = v.x * r * (1.f + s.x);
        o.y = v.y * r * (1.f + s.y);
        o.z = v.z * r * (1.f + s.z);
        o.w = v.w * r * (1.f + s.w);
        ((float4*)op)[c4] = o;
    }
}

// ---------------- fp32 GEMM  C[m,n] = sum_k A[m,k] * B[n,k] + bias[n] ----------------
// mode 0: write C (ld = Nc).  mode 1: scatter qkv columns into q/k/v buffers.
__global__ __launch_bounds__(256) void sgemm_nt_kernel(
    const float* __restrict__ A, const float* __restrict__ Bw,
    const float* __restrict__ bias, float* __restrict__ C,
    float* __restrict__ qp, float* __restrict__ kp, float* __restrict__ vp,
    int M, int Nc, int K, int mode, int row_off)
{
    __shared__ float As[16][132];
    __shared__ float Bs[16][132];
    const int tid = threadIdx.x;
    const int n0 = blockIdx.x * 128;
    const int m0 = blockIdx.y * 128;
    const int ty = tid >> 4, tx = tid & 15;
    const float* Ab = A + (size_t)m0 * K;
    const float* Bb = Bw + (size_t)n0 * K;
    float acc[8][8];
#pragma unroll
    for (int i = 0; i < 8; ++i)
#pragma unroll
        for (int j = 0; j < 8; ++j) acc[i][j] = 0.f;

    const int lrow = tid >> 2;  // 0..63
    const int lkq = tid & 3;    // 0..3

    for (int k0 = 0; k0 < K; k0 += 16) {
#pragma unroll
        for (int half = 0; half < 2; ++half) {
            const int row = lrow + half * 64;
            float4 a = *(const float4*)(Ab + (size_t)row * K + k0 + lkq * 4);
            float4 b = *(const float4*)(Bb + (size_t)row * K + k0 + lkq * 4);
            As[lkq * 4 + 0][row] = a.x; As[lkq * 4 + 1][row] = a.y;
            As[lkq * 4 + 2][row] = a.z; As[lkq * 4 + 3][row] = a.w;
            Bs[lkq * 4 + 0][row] = b.x; Bs[lkq * 4 + 1][row] = b.y;
            Bs[lkq * 4 + 2][row] = b.z; Bs[lkq * 4 + 3][row] = b.w;
        }
        __syncthreads();
#pragma unroll
        for (int kk = 0; kk < 16; ++kk) {
            float4 a0 = *(const float4*)&As[kk][ty * 8];
            float4 a1 = *(const float4*)&As[kk][ty * 8 + 4];
            float4 b0 = *(const float4*)&Bs[kk][tx * 8];
            float4 b1 = *(const float4*)&Bs[kk][tx * 8 + 4];
            float av[8] = {a0.x, a0.y, a0.z, a0.w, a1.x, a1.y, a1.z, a1.w};
            float bv[8] = {b0.x, b0.y, b0.z, b0.w, b1.x, b1.y, b1.z, b1.w};
#pragma unroll
            for (int i = 0; i < 8; ++i)
#pragma unroll
                for (int j = 0; j < 8; ++j)
                    acc[i][j] = fmaf(av[i], bv[j], acc[i][j]);
        }
        __syncthreads();
    }

    if (mode == 0) {
        const float* bp = bias + n0 + tx * 8;
        float b0 = bp[0], b1 = bp[1], b2 = bp[2], b3 = bp[3];
        float b4 = bp[4], b5 = bp[5], b6 = bp[6], b7 = bp[7];
#pragma unroll
        for (int i = 0; i < 8; ++i) {
            const int row = m0 + ty * 8 + i;
            float* cp = C + (size_t)row * Nc + n0 + tx * 8;
            float4 o0, o1;
            o0.x = acc[i][0] + b0; o0.y = acc[i][1] + b1;
            o0.z = acc[i][2] + b2; o0.w = acc[i][3] + b3;
            o1.x = acc[i][4] + b4; o1.y = acc[i][5] + b5;
            o1.z = acc[i][6] + b6; o1.w = acc[i][7] + b7;
            *(float4*)cp = o0;
            *(float4*)(cp + 4) = o1;
        }
    } else {
        const int part = n0 / DXC;
        const int cc0 = (n0 % DXC) + tx * 8;
        float* dst = (part == 0) ? qp : (part == 1) ? kp : vp;
        const float* bp = bias + n0 + tx * 8;
        float b0 = bp[0], b1 = bp[1], b2 = bp[2], b3 = bp[3];
        float b4 = bp[4], b5 = bp[5], b6 = bp[6], b7 = bp[7];
#pragma unroll
        for (int i = 0; i < 8; ++i) {
            const int row = row_off + m0 + ty * 8 + i;
            float* cp = dst + (size_t)row * DXC + cc0;
            float4 o0, o1;
            o0.x = acc[i][0] + b0; o0.y = acc[i][1] + b1;
            o0.z = acc[i][2] + b2; o0.w = acc[i][3] + b3;
            o1.x = acc[i][4] + b4; o1.y = acc[i][5] + b5;
            o1.z = acc[i][6] + b6; o1.w = acc[i][7] + b7;
            *(float4*)cp = o0;
            *(float4*)(cp + 4) = o1;
        }
    }
}

// ---------------- per-head rmsnorm (+ rope for x tokens) on q/k ----------------
__global__ __launch_bounds__(128) void qknorm_rope_kernel(
    float* __restrict__ qb, float* __restrict__ kb,
    const float* __restrict__ qnx, const float* __restrict__ knx,
    const float* __restrict__ qny, const float* __restrict__ kny,
    const float* __restrict__ cosp, const float* __restrict__ sinp)
{
    const int bx = blockIdx.x;
    const int which = bx & 1;            // 0=q, 1=k
    const int h = (bx >> 1) % NH;
    const int t = bx / (2 * NH);
    float* p = (which ? kb : qb) + (size_t)t * DXC + h * DH;
    const int d = threadIdx.x;
    const float v = p[d];
    float ss = v * v;
#pragma unroll
    for (int m = 1; m < 64; m <<= 1) ss += __shfl_xor(ss, m, 64);
    __shared__ float red[2];
    if ((d & 63) == 0) red[d >> 6] = ss;
    __syncthreads();
    const float tot = red[0] + red[1];
    const float r = rsqrtf(tot * (1.f / 128.f) + RMS_EPS);
    const float* w = (t < NX) ? (which ? knx : qnx) : (which ? kny : qny);
    const float nv = v * r * w[d];
    float outv = nv;
    if (t < NX) {
        const int pidx = d >> 1;
        const float cs = cosp[((size_t)t * NH + h) * 64 + pidx];
        const float sn = sinp[((size_t)t * NH + h) * 64 + pidx];
        const float partner = __shfl_xor(nv, 1, 64);
        outv = ((d & 1) == 0) ? (nv * cs - partner * sn)
                              : (partner * sn + nv * cs);
    }
    p[d] = outv;
}

// ---------------- flash attention, fp32 ----------------
#define BQ 64
#define BKV 64
#define NQT ((NTOT + BQ - 1) / BQ)   // 36

__global__ __launch_bounds__(256) void attn_kernel(
    const float* __restrict__ qb, const float* __restrict__ kb,
    const float* __restrict__ vb, float* __restrict__ outp,
    const int* __restrict__ idx)
{
    __shared__ float Qs[BQ * 128];    // 32 KB
    __shared__ float KVs[BKV * 128];  // 32 KB, shared between K and V phases
    const int h = blockIdx.x / NQT;
    const int qt = blockIdx.x % NQT;
    const int q0 = qt * BQ;
    const int tid = threadIdx.x;
    const int tq = tid >> 4;    // 0..15, owns q rows tq*4 .. tq*4+3
    const int tk = tid & 15;    // 0..15, owns kv cols tk*4 .. +3 (score phase), d cols tk*8..+7 (PV)
    const int lane = tid & 63;
    const int grpbase = lane & 48;

    // load Q tile (zero-fill invalid rows)
    for (int c = tid; c < BQ * 32; c += 256) {
        const int row = c >> 5, dc = c & 31;
        const int qi = q0 + row;
        float4 v = make_float4(0.f, 0.f, 0.f, 0.f);
        if (qi < NTOT) {
            const int tok = idx[qi];
            v = *(const float4*)(qb + (size_t)tok * DXC + h * DH + dc * 4);
        }
        *(float4*)&Qs[row * 128 + (dc ^ ((row >> 2) & 7)) * 4] = v;
    }

    float o[4][8];
    float m_i[4], l_i[4];
#pragma unroll
    for (int i = 0; i < 4; ++i) {
        m_i[i] = -INFINITY;
        l_i[i] = 0.f;
#pragma unroll
        for (int dd = 0; dd < 8; ++dd) o[i][dd] = 0.f;
    }

    for (int kv0 = 0; kv0 < NTOT; kv0 += BKV) {
        __syncthreads();  // previous V fully consumed
        // K tile
        for (int c = tid; c < BKV * 32; c += 256) {
            const int row = c >> 5, dc = c & 31;
            const int ki = kv0 + row;
            float4 v = make_float4(0.f, 0.f, 0.f, 0.f);
            if (ki < NTOT)
                v = *(const float4*)(kb + (size_t)idx[ki] * DXC + h * DH + dc * 4);
            *(float4*)&KVs[row * 128 + (dc ^ ((row >> 2) & 7)) * 4] = v;
        }
        __syncthreads();

        float s[4][4];
#pragma unroll
        for (int i = 0; i < 4; ++i)
#pragma unroll
            for (int j = 0; j < 4; ++j) s[i][j] = 0.f;
        const int qsw = tq & 7;
        const int ksw = tk & 7;
#pragma unroll 8
        for (int dc = 0; dc < 32; ++dc) {
            float4 qv[4], kvv[4];
#pragma unroll
            for (int i = 0; i < 4; ++i)
                qv[i] = *(const float4*)&Qs[(tq * 4 + i) * 128 + ((dc ^ qsw) * 4)];
#pragma unroll
            for (int j = 0; j < 4; ++j)
                kvv[j] = *(const float4*)&KVs[(tk * 4 + j) * 128 + ((dc ^ ksw) * 4)];
#pragma unroll
            for (int i = 0; i < 4; ++i)
#pragma unroll
                for (int j = 0; j < 4; ++j)
                    s[i][j] += qv[i].x * kvv[j].x + qv[i].y * kvv[j].y +
                               qv[i].z * kvv[j].z + qv[i].w * kvv[j].w;
        }

        float p[4][4], alpha[4];
#pragma unroll
        for (int i = 0; i < 4; ++i) {
            float mt = -INFINITY;
#pragma unroll
            for (int j = 0; j < 4; ++j) {
                s[i][j] *= 0.08838834764831845f;  // 1/sqrt(128)
                if (kv0 + tk * 4 + j >= NTOT) s[i][j] = -INFINITY;
                mt = fmaxf(mt, s[i][j]);
            }
#pragma unroll
            for (int mm = 1; mm < 16; mm <<= 1) mt = fmaxf(mt, __shfl_xor(mt, mm, 64));
            const float mn = fmaxf(m_i[i], mt);
            alpha[i] = __expf(m_i[i] - mn);
            m_i[i] = mn;
            float rs = 0.f;
#pragma unroll
            for (int j = 0; j < 4; ++j) {
                p[i][j] = __expf(s[i][j] - mn);
                rs += p[i][j];
            }
#pragma unroll
            for (int mm = 1; mm < 16; mm <<= 1) rs += __shfl_xor(rs, mm, 64);
            l_i[i] = l_i[i] * alpha[i] + rs;
        }

        __syncthreads();  // done reading K
        // V tile (overwrite K in LDS)
        for (int c = tid; c < BKV * 32; c += 256) {
            const int row = c >> 5, dc = c & 31;
            const int ki = kv0 + row;
            float4 v = make_float4(0.f, 0.f, 0.f, 0.f);
            if (ki < NTOT)
                v = *(const float4*)(vb + (size_t)idx[ki] * DXC + h * DH + dc * 4);
            *(float4*)&KVs[row * 128 + (dc ^ ((row >> 2) & 7)) * 4] = v;
        }
        __syncthreads();

#pragma unroll
        for (int i = 0; i < 4; ++i)
#pragma unroll
            for (int dd = 0; dd < 8; ++dd) o[i][dd] *= alpha[i];

        const int c0 = 2 * tk, c1 = 2 * tk + 1;
#pragma unroll 4
        for (int j0 = 0; j0 < BKV; j0 += 4) {
            const int src = grpbase + (j0 >> 2);
#pragma unroll
            for (int jj = 0; jj < 4; ++jj) {
                const int jr = j0 + jj;
                const int sw = (jr >> 2) & 7;
                float4 v0 = *(const float4*)&KVs[jr * 128 + ((c0 ^ sw) * 4)];
                float4 v1 = *(const float4*)&KVs[jr * 128 + ((c1 ^ sw) * 4)];
#pragma unroll
                for (int i = 0; i < 4; ++i) {
                    const float pv = __shfl(p[i][jj], src, 64);
                    o[i][0] = fmaf(pv, v0.x, o[i][0]);
                    o[i][1] = fmaf(pv, v0.y, o[i][1]);
                    o[i][2] = fmaf(pv, v0.z, o[i][2]);
                    o[i][3] = fmaf(pv, v0.w, o[i][3]);
                    o[i][4] = fmaf(pv, v1.x, o[i][4]);
                    o[i][5] = fmaf(pv, v1.y, o[i][5]);
                    o[i][6] = fmaf(pv, v1.z, o[i][6]);
                    o[i][7] = fmaf(pv, v1.w, o[i][7]);
                }
            }
        }
    }

#pragma unroll
    for (int i = 0; i < 4; ++i) {
        const int qi = q0 + tq * 4 + i;
        if (qi >= NTOT) continue;
        const int tok = idx[qi];
        const float inv = 1.f / l_i[i];
        float* op = outp + (size_t)tok * DXC + h * DH + tk * 8;
        float4 o0, o1;
        o0.x = o[i][0] * inv; o0.y = o[i][1] * inv;
        o0.z = o[i][2] * inv; o0.w = o[i][3] * inv;
        o1.x = o[i][4] * inv; o1.y = o[i][5] * inv;
        o1.z = o[i][6] * inv; o1.w = o[i][7] * inv;
        *(float4*)op = o0;
        *(float4*)(op + 4) = o1;
    }
}

extern "C" void kernel_launch(void* const* d_in, const int* in_sizes, int n_in,
                              void* d_out, int out_size, void* d_ws, size_t ws_size,
                              hipStream_t stream)
{
    const float* x        = (const float*)d_in[0];
    const float* y        = (const float*)d_in[1];
    const float* scale_x  = (const float*)d_in[2];
    const float* scale_y  = (const float*)d_in[3];
    const float* rope_cos = (const float*)d_in[4];
    const float* rope_sin = (const float*)d_in[5];
    const float* W_qkv_x  = (const float*)d_in[6];
    const float* b_qkv_x  = (const float*)d_in[7];
    const float* W_qkv_y  = (const float*)d_in[8];
    const float* b_qkv_y  = (const float*)d_in[9];
    const float* q_norm_x = (const float*)d_in[10];
    const float* k_norm_x = (const float*)d_in[11];
    const float* q_norm_y = (const float*)d_in[12];
    const float* k_norm_y = (const float*)d_in[13];
    const float* W_proj_x = (const float*)d_in[14];
    const float* b_proj_x = (const float*)d_in[15];
    const float* W_proj_y = (const float*)d_in[16];
    const float* b_proj_y = (const float*)d_in[17];
    const int*   vidx     = (const int*)d_in[18];
    float* out = (float*)d_out;

    float* ws = (float*)d_ws;
    const size_t SEG = (size_t)NLTOK * DXC;  // 7,077,888 floats
    float* attn = ws;              // also holds xm/ym in phase 1
    float* qbuf = ws + SEG;
    float* kbuf = ws + 2 * SEG;
    float* vbuf = ws + 3 * SEG;
    float* xm = attn;
    float* ym = attn + (size_t)NX * DXC;  // 6,291,456 + 393,216 <= SEG

    // 1) rmsnorm * (1 + scale)
    rmsnorm_scale_kernel<<<NX, 256, 0, stream>>>(x, scale_x, xm, DXC);
    rmsnorm_scale_kernel<<<LY, 256, 0, stream>>>(y, scale_y, ym, DYC);

    // 2) QKV GEMMs, scattering columns into q/k/v token buffers
    sgemm_nt_kernel<<<dim3(9216 / 128, NX / 128), 256, 0, stream>>>(
        xm, W_qkv_x, b_qkv_x, nullptr, qbuf, kbuf, vbuf, NX, 9216, DXC, 1, 0);
    sgemm_nt_kernel<<<dim3(9216 / 128, LY / 128), 256, 0, stream>>>(
        ym, W_qkv_y, b_qkv_y, nullptr, qbuf, kbuf, vbuf, LY, 9216, DYC, 1, NX);

    // 3) per-head q/k rmsnorm (+rope for x tokens)
    qknorm_rope_kernel<<<NLTOK * NH * 2, 128, 0, stream>>>(
        qbuf, kbuf, q_norm_x, k_norm_x, q_norm_y, k_norm_y, rope_cos, rope_sin);

    // 4) zero the scatter target (xm/ym dead now)
    hipMemsetAsync(attn, 0, SEG * sizeof(float), stream);

    // 5) flash attention with gather/scatter through valid_token_indices
    attn_kernel<<<NH * NQT, 256, 0, stream>>>(qbuf, kbuf, vbuf, attn, vidx);

    // 6) output projections
    sgemm_nt_kernel<<<dim3(DXC / 128, NX / 128), 256, 0, stream>>>(
        attn, W_proj_x, b_proj_x, out, nullptr, nullptr, nullptr, NX, DXC, DXC, 0, 0);
    sgemm_nt_kernel<<<dim3(DYC / 128, LY / 128), 256, 0, stream>>>(
        attn + (size_t)NX * DXC, W_proj_y, b_proj_y, out + (size_t)NX * DXC,
        nullptr, nullptr, nullptr, LY, DYC, DXC, 0, 0);
}

// Round 2
// 3322.828 us; speedup vs baseline: 2.0770x; 2.0770x over previous
//
#include <hip/hip_runtime.h>
#include <math.h>

#define NX 2048
#define LY 256
#define NH 24
#define DH 128
#define DXC 3072
#define DYC 1536
#define NLTOK 2304
#define NTOT 2248
#define RMS_EPS 1e-6f

typedef __bf16 bf16x8 __attribute__((ext_vector_type(8)));
typedef float f32x4 __attribute__((ext_vector_type(4)));

static __device__ __forceinline__ unsigned short f2bf(float f) {
    union { float f; unsigned int u; } x; x.f = f;
    unsigned int r = (x.u + 0x7fffu + ((x.u >> 16) & 1u)) >> 16;
    return (unsigned short)r;
}
static __device__ __forceinline__ float bf2f(unsigned short u) {
    union { unsigned int u; float f; } x; x.u = ((unsigned int)u) << 16;
    return x.f;
}
static __device__ __forceinline__ unsigned int pack2(float lo, float hi) {
    return (unsigned int)f2bf(lo) | ((unsigned int)f2bf(hi) << 16);
}

// ---------------- rmsnorm * (1 + scale) ----------------
__global__ __launch_bounds__(256) void rmsnorm_scale_kernel(
    const float* __restrict__ in, const float* __restrict__ scale,
    float* __restrict__ out, int cols)
{
    const int row = blockIdx.x;
    const int tid = threadIdx.x;
    const float* rp = in + (size_t)row * cols;
    const int nv = cols >> 2;
    float4 vals[3];
    float ss = 0.f;
    int cnt = 0;
    for (int c4 = tid; c4 < nv; c4 += 256) {
        float4 v = ((const float4*)rp)[c4];
        vals[cnt++] = v;
        ss += v.x * v.x + v.y * v.y + v.z * v.z + v.w * v.w;
    }
#pragma unroll
    for (int m = 1; m < 64; m <<= 1) ss += __shfl_xor(ss, m, 64);
    __shared__ float red[4];
    if ((tid & 63) == 0) red[tid >> 6] = ss;
    __syncthreads();
    const float tot = red[0] + red[1] + red[2] + red[3];
    const float r = rsqrtf(tot / (float)cols + RMS_EPS);
    float* op = out + (size_t)row * cols;
    cnt = 0;
    for (int c4 = tid; c4 < nv; c4 += 256) {
        float4 v = vals[cnt++];
        float4 s = ((const float4*)scale)[c4];
        float4 o;
        o.x = v.x * r * (1.f + s.x);
        o.y = v.y * r * (1.f + s.y);
        o.z = v.z * r * (1.f + s.z);
        o.w = v.w * r * (1.f + s.w);
        ((float4*)op)[c4] = o;
    }
}

// ---------------- fp32 GEMM  C[m,n] = sum_k A[m,k] * B[n,k] + bias[n] ----------------
// mode 0: write fp32 C (ld = Nc).  mode 1: scatter qkv columns into bf16 q/k/v buffers.
__global__ __launch_bounds__(256) void sgemm_nt_kernel(
    const float* __restrict__ A, const float* __restrict__ Bw,
    const float* __restrict__ bias, float* __restrict__ C,
    unsigned short* __restrict__ qp, unsigned short* __restrict__ kp,
    unsigned short* __restrict__ vp,
    int M, int Nc, int K, int mode, int row_off)
{
    __shared__ float As[16][132];
    __shared__ float Bs[16][132];
    const int tid = threadIdx.x;
    const int n0 = blockIdx.x * 128;
    const int m0 = blockIdx.y * 128;
    const int ty = tid >> 4, tx = tid & 15;
    const float* Ab = A + (size_t)m0 * K;
    const float* Bb = Bw + (size_t)n0 * K;
    float acc[8][8];
#pragma unroll
    for (int i = 0; i < 8; ++i)
#pragma unroll
        for (int j = 0; j < 8; ++j) acc[i][j] = 0.f;

    const int lrow = tid >> 2;
    const int lkq = tid & 3;

    for (int k0 = 0; k0 < K; k0 += 16) {
#pragma unroll
        for (int half = 0; half < 2; ++half) {
            const int row = lrow + half * 64;
            float4 a = *(const float4*)(Ab + (size_t)row * K + k0 + lkq * 4);
            float4 b = *(const float4*)(Bb + (size_t)row * K + k0 + lkq * 4);
            As[lkq * 4 + 0][row] = a.x; As[lkq * 4 + 1][row] = a.y;
            As[lkq * 4 + 2][row] = a.z; As[lkq * 4 + 3][row] = a.w;
            Bs[lkq * 4 + 0][row] = b.x; Bs[lkq * 4 + 1][row] = b.y;
            Bs[lkq * 4 + 2][row] = b.z; Bs[lkq * 4 + 3][row] = b.w;
        }
        __syncthreads();
#pragma unroll
        for (int kk = 0; kk < 16; ++kk) {
            float4 a0 = *(const float4*)&As[kk][ty * 8];
            float4 a1 = *(const float4*)&As[kk][ty * 8 + 4];
            float4 b0 = *(const float4*)&Bs[kk][tx * 8];
            float4 b1 = *(const float4*)&Bs[kk][tx * 8 + 4];
            float av[8] = {a0.x, a0.y, a0.z, a0.w, a1.x, a1.y, a1.z, a1.w};
            float bv[8] = {b0.x, b0.y, b0.z, b0.w, b1.x, b1.y, b1.z, b1.w};
#pragma unroll
            for (int i = 0; i < 8; ++i)
#pragma unroll
                for (int j = 0; j < 8; ++j)
                    acc[i][j] = fmaf(av[i], bv[j], acc[i][j]);
        }
        __syncthreads();
    }

    const float* bp = bias + n0 + tx * 8;
    float b0 = bp[0], b1 = bp[1], b2 = bp[2], b3 = bp[3];
    float b4 = bp[4], b5 = bp[5], b6 = bp[6], b7 = bp[7];
    if (mode == 0) {
#pragma unroll
        for (int i = 0; i < 8; ++i) {
            const int row = m0 + ty * 8 + i;
            float* cp = C + (size_t)row * Nc + n0 + tx * 8;
            float4 o0, o1;
            o0.x = acc[i][0] + b0; o0.y = acc[i][1] + b1;
            o0.z = acc[i][2] + b2; o0.w = acc[i][3] + b3;
            o1.x = acc[i][4] + b4; o1.y = acc[i][5] + b5;
            o1.z = acc[i][6] + b6; o1.w = acc[i][7] + b7;
            *(float4*)cp = o0;
            *(float4*)(cp + 4) = o1;
        }
    } else {
        const int part = n0 / DXC;
        const int cc0 = (n0 % DXC) + tx * 8;
        unsigned short* dst = (part == 0) ? qp : (part == 1) ? kp : vp;
#pragma unroll
        for (int i = 0; i < 8; ++i) {
            const int row = row_off + m0 + ty * 8 + i;
            unsigned short* cp = dst + (size_t)row * DXC + cc0;
            uint4 o;
            o.x = pack2(acc[i][0] + b0, acc[i][1] + b1);
            o.y = pack2(acc[i][2] + b2, acc[i][3] + b3);
            o.z = pack2(acc[i][4] + b4, acc[i][5] + b5);
            o.w = pack2(acc[i][6] + b6, acc[i][7] + b7);
            *(uint4*)cp = o;
        }
    }
}

// ---------------- per-head rmsnorm (+ rope for x tokens) on bf16 q/k ----------------
__global__ __launch_bounds__(128) void qknorm_rope_kernel(
    unsigned short* __restrict__ qb, unsigned short* __restrict__ kb,
    const float* __restrict__ qnx, const float* __restrict__ knx,
    const float* __restrict__ qny, const float* __restrict__ kny,
    const float* __restrict__ cosp, const float* __restrict__ sinp)
{
    const int bx = blockIdx.x;
    const int which = bx & 1;
    const int h = (bx >> 1) % NH;
    const int t = bx / (2 * NH);
    unsigned short* p = (which ? kb : qb) + (size_t)t * DXC + h * DH;
    const int d = threadIdx.x;
    const float v = bf2f(p[d]);
    float ss = v * v;
#pragma unroll
    for (int m = 1; m < 64; m <<= 1) ss += __shfl_xor(ss, m, 64);
    __shared__ float red[2];
    if ((d & 63) == 0) red[d >> 6] = ss;
    __syncthreads();
    const float tot = red[0] + red[1];
    const float r = rsqrtf(tot * (1.f / 128.f) + RMS_EPS);
    const float* w = (t < NX) ? (which ? knx : qnx) : (which ? kny : qny);
    const float nv = v * r * w[d];
    float outv = nv;
    if (t < NX) {
        const int pidx = d >> 1;
        const float cs = cosp[((size_t)t * NH + h) * 64 + pidx];
        const float sn = sinp[((size_t)t * NH + h) * 64 + pidx];
        const float partner = __shfl_xor(nv, 1, 64);
        outv = ((d & 1) == 0) ? (nv * cs - partner * sn)
                              : (partner * sn + nv * cs);
    }
    p[d] = f2bf(outv);
}

// ---------------- flash attention, bf16 MFMA 16x16x32 ----------------
#define BQ 64
#define BKV 64
#define NQT ((NTOT + BQ - 1) / BQ)   // 36
#define ATTN_SCALE 0.08838834764831845f

__global__ __launch_bounds__(256) void attn_kernel(
    const unsigned short* __restrict__ qb, const unsigned short* __restrict__ kb,
    const unsigned short* __restrict__ vb, float* __restrict__ outp,
    const int* __restrict__ idx)
{
    __shared__ unsigned short Qs[64 * 136];      // 17408 B, row stride 272 B
    __shared__ unsigned short Ks[64 * 136];      // 17408 B
    __shared__ unsigned int   Vt[128 * 36];      // 18432 B, Vt[d][kvpair], pairs (2p,2p+1)
    __shared__ unsigned short Ps[4][16 * 72];    // 9216 B, per-wave P in [q][kv]

    const int h  = blockIdx.x / NQT;
    const int qt = blockIdx.x % NQT;
    const int q0 = qt * BQ;
    const int tid  = threadIdx.x;
    const int wave = tid >> 6;
    const int lane = tid & 63;
    const int quad = lane >> 4;
    const int ln   = lane & 15;

    // ---- stage Q tile ----
    for (int c = tid; c < 64 * 16; c += 256) {
        const int row = c >> 4, ch = c & 15;
        const int qi = q0 + row;
        uint4 v = make_uint4(0, 0, 0, 0);
        if (qi < NTOT) {
            const int tok = idx[qi];
            v = *(const uint4*)(qb + (size_t)tok * DXC + h * DH + ch * 8);
        }
        *(uint4*)&Qs[row * 136 + ch * 8] = v;
    }
    __syncthreads();

    // ---- Q A-frags: A[m=ln][k=quad*8+j], strip row = wave*16+ln ----
    bf16x8 aq[4];
#pragma unroll
    for (int c = 0; c < 4; ++c)
        aq[c] = __builtin_bit_cast(bf16x8,
            *(const uint4*)&Qs[(wave * 16 + ln) * 136 + c * 32 + quad * 8]);

    f32x4 o[8];
#pragma unroll
    for (int dt = 0; dt < 8; ++dt) o[dt] = (f32x4){0.f, 0.f, 0.f, 0.f};
    float m_i[4] = {-1e30f, -1e30f, -1e30f, -1e30f};
    float l_i[4] = {0.f, 0.f, 0.f, 0.f};

    for (int kv0 = 0; kv0 < NTOT; kv0 += BKV) {
        __syncthreads();   // previous tile's Ks/Vt reads done
        // ---- stage K tile [kv][d] ----
        for (int c = tid; c < 64 * 16; c += 256) {
            const int row = c >> 4, ch = c & 15;
            const int ki = kv0 + row;
            uint4 v = make_uint4(0, 0, 0, 0);
            if (ki < NTOT)
                v = *(const uint4*)(kb + (size_t)idx[ki] * DXC + h * DH + ch * 8);
            *(uint4*)&Ks[row * 136 + ch * 8] = v;
        }
        // ---- stage V tile transposed pair-packed: Vt[d][p] = (V[2p][d], V[2p+1][d]) ----
#pragma unroll
        for (int it = 0; it < 2; ++it) {
            const int pr = (tid >> 4) + it * 16;   // kv pair 0..31
            const int ch = tid & 15;               // d-chunk of 8
            const int k0i = kv0 + pr * 2, k1i = k0i + 1;
            uint4 a = make_uint4(0, 0, 0, 0), b = make_uint4(0, 0, 0, 0);
            if (k0i < NTOT)
                a = *(const uint4*)(vb + (size_t)idx[k0i] * DXC + h * DH + ch * 8);
            if (k1i < NTOT)
                b = *(const uint4*)(vb + (size_t)idx[k1i] * DXC + h * DH + ch * 8);
            unsigned int w[8];
            w[0] = (a.x & 0xffffu) | (b.x << 16);  w[1] = (a.x >> 16) | (b.x & 0xffff0000u);
            w[2] = (a.y & 0xffffu) | (b.y << 16);  w[3] = (a.y >> 16) | (b.y & 0xffff0000u);
            w[4] = (a.z & 0xffffu) | (b.z << 16);  w[5] = (a.z >> 16) | (b.z & 0xffff0000u);
            w[6] = (a.w & 0xffffu) | (b.w << 16);  w[7] = (a.w >> 16) | (b.w & 0xffff0000u);
#pragma unroll
            for (int s = 0; s < 8; ++s) {
                const int e = (s + ch) & 7;        // rotate to spread banks
                Vt[(ch * 8 + e) * 36 + pr] = w[e];
            }
        }
        __syncthreads();

        // ---- scores: S[q][kv], 4 n-tiles of 16 kv ----
        f32x4 sc[4];
#pragma unroll
        for (int t = 0; t < 4; ++t) {
            sc[t] = (f32x4){0.f, 0.f, 0.f, 0.f};
#pragma unroll
            for (int c = 0; c < 4; ++c) {
                bf16x8 bk = __builtin_bit_cast(bf16x8,
                    *(const uint4*)&Ks[(t * 16 + ln) * 136 + c * 32 + quad * 8]);
                sc[t] = __builtin_amdgcn_mfma_f32_16x16x32_bf16(aq[c], bk, sc[t], 0, 0, 0);
            }
        }

        // ---- online softmax (rows q = quad*4+r, cols kv = t*16+ln) ----
        float alpha[4];
#pragma unroll
        for (int r = 0; r < 4; ++r) {
            float mt = -1e30f;
#pragma unroll
            for (int t = 0; t < 4; ++t) {
                float sv = sc[t][r] * ATTN_SCALE;
                if (kv0 + t * 16 + ln >= NTOT) sv = -1e30f;
                sc[t][r] = sv;
                mt = fmaxf(mt, sv);
            }
#pragma unroll
            for (int mm = 1; mm < 16; mm <<= 1) mt = fmaxf(mt, __shfl_xor(mt, mm, 64));
            const float mn = fmaxf(m_i[r], mt);
            alpha[r] = __expf(m_i[r] - mn);
            m_i[r] = mn;
            float rs = 0.f;
#pragma unroll
            for (int t = 0; t < 4; ++t) {
                const float pv = __expf(sc[t][r] - mn);
                sc[t][r] = pv;
                rs += pv;
            }
#pragma unroll
            for (int mm = 1; mm < 16; mm <<= 1) rs += __shfl_xor(rs, mm, 64);
            l_i[r] = l_i[r] * alpha[r] + rs;
        }

        // ---- P: C-layout -> A-layout via per-wave LDS ----
        unsigned short* psw = Ps[wave];
#pragma unroll
        for (int t = 0; t < 4; ++t)
#pragma unroll
            for (int r = 0; r < 4; ++r)
                psw[(quad * 4 + r) * 72 + t * 16 + ln] = f2bf(sc[t][r]);

        // ---- rescale O ----
#pragma unroll
        for (int dt = 0; dt < 8; ++dt)
#pragma unroll
            for (int r = 0; r < 4; ++r) o[dt][r] *= alpha[r];

        // ---- PV: O[q][d] += P[q][kv] * V[kv][d] ----
        bf16x8 ap0 = __builtin_bit_cast(bf16x8, *(const uint4*)&psw[ln * 72 + quad * 8]);
        bf16x8 ap1 = __builtin_bit_cast(bf16x8, *(const uint4*)&psw[ln * 72 + 32 + quad * 8]);
#pragma unroll
        for (int dt = 0; dt < 8; ++dt) {
            bf16x8 bv0 = __builtin_bit_cast(bf16x8,
                *(const uint4*)&Vt[(dt * 16 + ln) * 36 + quad * 4]);
            o[dt] = __builtin_amdgcn_mfma_f32_16x16x32_bf16(ap0, bv0, o[dt], 0, 0, 0);
            bf16x8 bv1 = __builtin_bit_cast(bf16x8,
                *(const uint4*)&Vt[(dt * 16 + ln) * 36 + 16 + quad * 4]);
            o[dt] = __builtin_amdgcn_mfma_f32_16x16x32_bf16(ap1, bv1, o[dt], 0, 0, 0);
        }
    }

    // ---- epilogue: scatter O rows ----
#pragma unroll
    for (int r = 0; r < 4; ++r) {
        const int qrow = q0 + wave * 16 + quad * 4 + r;
        if (qrow >= NTOT) continue;
        const int tok = idx[qrow];
        const float inv = 1.f / l_i[r];
        float* op = outp + (size_t)tok * DXC + h * DH + ln;
#pragma unroll
        for (int dt = 0; dt < 8; ++dt)
            op[dt * 16] = o[dt][r] * inv;
    }
}

extern "C" void kernel_launch(void* const* d_in, const int* in_sizes, int n_in,
                              void* d_out, int out_size, void* d_ws, size_t ws_size,
                              hipStream_t stream)
{
    const float* x        = (const float*)d_in[0];
    const float* y        = (const float*)d_in[1];
    const float* scale_x  = (const float*)d_in[2];
    const float* scale_y  = (const float*)d_in[3];
    const float* rope_cos = (const float*)d_in[4];
    const float* rope_sin = (const float*)d_in[5];
    const float* W_qkv_x  = (const float*)d_in[6];
    const float* b_qkv_x  = (const float*)d_in[7];
    const float* W_qkv_y  = (const float*)d_in[8];
    const float* b_qkv_y  = (const float*)d_in[9];
    const float* q_norm_x = (const float*)d_in[10];
    const float* k_norm_x = (const float*)d_in[11];
    const float* q_norm_y = (const float*)d_in[12];
    const float* k_norm_y = (const float*)d_in[13];
    const float* W_proj_x = (const float*)d_in[14];
    const float* b_proj_x = (const float*)d_in[15];
    const float* W_proj_y = (const float*)d_in[16];
    const float* b_proj_y = (const float*)d_in[17];
    const int*   vidx     = (const int*)d_in[18];
    float* out = (float*)d_out;

    float* ws = (float*)d_ws;
    const size_t SEG = (size_t)NLTOK * DXC;  // 7,077,888 elements
    float* attn = ws;                        // fp32, also xm/ym in phase 1
    unsigned short* q16 = (unsigned short*)(ws + SEG);
    unsigned short* k16 = q16 + SEG;
    unsigned short* v16 = k16 + SEG;
    float* xm = attn;
    float* ym = attn + (size_t)NX * DXC;

    // 1) rmsnorm * (1 + scale)
    rmsnorm_scale_kernel<<<NX, 256, 0, stream>>>(x, scale_x, xm, DXC);
    rmsnorm_scale_kernel<<<LY, 256, 0, stream>>>(y, scale_y, ym, DYC);

    // 2) QKV GEMMs (fp32 accum), scatter into bf16 q/k/v token buffers
    sgemm_nt_kernel<<<dim3(9216 / 128, NX / 128), 256, 0, stream>>>(
        xm, W_qkv_x, b_qkv_x, nullptr, q16, k16, v16, NX, 9216, DXC, 1, 0);
    sgemm_nt_kernel<<<dim3(9216 / 128, LY / 128), 256, 0, stream>>>(
        ym, W_qkv_y, b_qkv_y, nullptr, q16, k16, v16, LY, 9216, DYC, 1, NX);

    // 3) per-head q/k rmsnorm (+rope for x tokens), in-place bf16
    qknorm_rope_kernel<<<NLTOK * NH * 2, 128, 0, stream>>>(
        q16, k16, q_norm_x, k_norm_x, q_norm_y, k_norm_y, rope_cos, rope_sin);

    // 4) zero the attention scatter target (xm/ym dead now)
    hipMemsetAsync(attn, 0, SEG * sizeof(float), stream);

    // 5) flash attention (bf16 MFMA) with gather/scatter via valid_token_indices
    attn_kernel<<<NH * NQT, 256, 0, stream>>>(q16, k16, v16, attn, vidx);

    // 6) output projections (fp32)
    sgemm_nt_kernel<<<dim3(DXC / 128, NX / 128), 256, 0, stream>>>(
        attn, W_proj_x, b_proj_x, out, nullptr, nullptr, nullptr, NX, DXC, DXC, 0, 0);
    sgemm_nt_kernel<<<dim3(DYC / 128, LY / 128), 256, 0, stream>>>(
        attn + (size_t)NX * DXC, W_proj_y, b_proj_y, out + (size_t)NX * DXC,
        nullptr, nullptr, nullptr, LY, DYC, DXC, 0, 0);
}

// Round 3
// 1560.847 us; speedup vs baseline: 4.4216x; 2.1289x over previous
//
#include <hip/hip_runtime.h>
#include <math.h>

#define NX 2048
#define LY 256
#define NH 24
#define DH 128
#define DXC 3072
#define DYC 1536
#define NLTOK 2304
#define NTOT 2248
#define RMS_EPS 1e-6f

typedef __bf16 bf16x8 __attribute__((ext_vector_type(8)));
typedef float f32x4 __attribute__((ext_vector_type(4)));

static __device__ __forceinline__ unsigned short f2bf(float f) {
    union { float f; unsigned int u; } x; x.f = f;
    unsigned int r = (x.u + 0x7fffu + ((x.u >> 16) & 1u)) >> 16;
    return (unsigned short)r;
}
static __device__ __forceinline__ float bf2f(unsigned short u) {
    union { unsigned int u; float f; } x; x.u = ((unsigned int)u) << 16;
    return x.f;
}
static __device__ __forceinline__ unsigned int pack2(float lo, float hi) {
    return (unsigned int)f2bf(lo) | ((unsigned int)f2bf(hi) << 16);
}
// split fp32 -> hi (truncate) + lo (RN of remainder); residual <= 2^-17 |x|
static __device__ __forceinline__ void split4(float4 f, uint2& h, uint2& l) {
    unsigned int ux = __float_as_uint(f.x), uy = __float_as_uint(f.y);
    unsigned int uz = __float_as_uint(f.z), uw = __float_as_uint(f.w);
    h.x = (ux >> 16) | (uy & 0xffff0000u);
    h.y = (uz >> 16) | (uw & 0xffff0000u);
    float lx = f.x - __uint_as_float(ux & 0xffff0000u);
    float ly = f.y - __uint_as_float(uy & 0xffff0000u);
    float lz = f.z - __uint_as_float(uz & 0xffff0000u);
    float lw = f.w - __uint_as_float(uw & 0xffff0000u);
    l.x = pack2(lx, ly);
    l.y = pack2(lz, lw);
}

// ---------------- rmsnorm * (1 + scale) -> split bf16 hi/lo ----------------
__global__ __launch_bounds__(256) void rmsnorm_scale_split_kernel(
    const float* __restrict__ in, const float* __restrict__ scale,
    unsigned short* __restrict__ out_hi, unsigned short* __restrict__ out_lo,
    int cols)
{
    const int row = blockIdx.x;
    const int tid = threadIdx.x;
    const float* rp = in + (size_t)row * cols;
    const int nv = cols >> 2;
    float4 vals[3];
    float ss = 0.f;
    int cnt = 0;
    for (int c4 = tid; c4 < nv; c4 += 256) {
        float4 v = ((const float4*)rp)[c4];
        vals[cnt++] = v;
        ss += v.x * v.x + v.y * v.y + v.z * v.z + v.w * v.w;
    }
#pragma unroll
    for (int m = 1; m < 64; m <<= 1) ss += __shfl_xor(ss, m, 64);
    __shared__ float red[4];
    if ((tid & 63) == 0) red[tid >> 6] = ss;
    __syncthreads();
    const float tot = red[0] + red[1] + red[2] + red[3];
    const float r = rsqrtf(tot / (float)cols + RMS_EPS);
    unsigned short* oh = out_hi + (size_t)row * cols;
    unsigned short* ol = out_lo + (size_t)row * cols;
    cnt = 0;
    for (int c4 = tid; c4 < nv; c4 += 256) {
        float4 v = vals[cnt++];
        float4 s = ((const float4*)scale)[c4];
        float4 o;
        o.x = v.x * r * (1.f + s.x);
        o.y = v.y * r * (1.f + s.y);
        o.z = v.z * r * (1.f + s.z);
        o.w = v.w * r * (1.f + s.w);
        uint2 h, l;
        split4(o, h, l);
        ((uint2*)oh)[c4] = h;
        ((uint2*)ol)[c4] = l;
    }
}

// ---------------- split-bf16 3-term MFMA GEMM ----------------
// C[m,n] = sum_k A[m,k]*B[n,k] + bias[n]; A pre-split (hi/lo bf16), B fp32
// split in-kernel. mode 0: fp32 C (ld=Nc). mode 1: bf16 scatter to q/k/v.
__global__ __launch_bounds__(256) void gemm_split_kernel(
    const unsigned short* __restrict__ Ahg, const unsigned short* __restrict__ Alg,
    const float* __restrict__ Bg, const float* __restrict__ bias,
    float* __restrict__ C,
    unsigned short* __restrict__ qp, unsigned short* __restrict__ kp,
    unsigned short* __restrict__ vp,
    int Nc, int K, int mode, int row_off)
{
    __shared__ unsigned short Ah[128 * 40];   // rows stride 40 (80B): b128 reads 2-way
    __shared__ unsigned short Al[128 * 40];
    __shared__ unsigned short Bh[128 * 40];
    __shared__ unsigned short Bl[128 * 40];

    const int tid = threadIdx.x;
    const int n0 = blockIdx.x * 128;
    const int m0 = blockIdx.y * 128;
    const int wave = tid >> 6, lane = tid & 63;
    const int quad = lane >> 4, ln = lane & 15;
    const int wm = wave >> 1, wn = wave & 1;
    const int sr = tid >> 1;            // staged row 0..127
    const int sk = (tid & 1) * 16;      // k-half (elements)

    const unsigned short* Abh = Ahg + (size_t)(m0 + sr) * K + sk;
    const unsigned short* Abl = Alg + (size_t)(m0 + sr) * K + sk;
    const float* Bb = Bg + (size_t)(n0 + sr) * K + sk;

    f32x4 acc[4][4];
#pragma unroll
    for (int i = 0; i < 4; ++i)
#pragma unroll
        for (int j = 0; j < 4; ++j) acc[i][j] = (f32x4){0.f, 0.f, 0.f, 0.f};

    // prefetch k0 = 0
    uint4 pah0 = *(const uint4*)Abh;
    uint4 pah1 = *(const uint4*)(Abh + 8);
    uint4 pal0 = *(const uint4*)Abl;
    uint4 pal1 = *(const uint4*)(Abl + 8);
    float4 pb0 = ((const float4*)Bb)[0];
    float4 pb1 = ((const float4*)Bb)[1];
    float4 pb2 = ((const float4*)Bb)[2];
    float4 pb3 = ((const float4*)Bb)[3];

    for (int k0 = 0; k0 < K; k0 += 32) {
        __syncthreads();   // previous fragment reads done
        *(uint4*)&Ah[sr * 40 + sk]     = pah0;
        *(uint4*)&Ah[sr * 40 + sk + 8] = pah1;
        *(uint4*)&Al[sr * 40 + sk]     = pal0;
        *(uint4*)&Al[sr * 40 + sk + 8] = pal1;
        uint2 h0, l0, h1, l1, h2, l2, h3, l3;
        split4(pb0, h0, l0); split4(pb1, h1, l1);
        split4(pb2, h2, l2); split4(pb3, h3, l3);
        *(uint4*)&Bh[sr * 40 + sk]     = make_uint4(h0.x, h0.y, h1.x, h1.y);
        *(uint4*)&Bh[sr * 40 + sk + 8] = make_uint4(h2.x, h2.y, h3.x, h3.y);
        *(uint4*)&Bl[sr * 40 + sk]     = make_uint4(l0.x, l0.y, l1.x, l1.y);
        *(uint4*)&Bl[sr * 40 + sk + 8] = make_uint4(l2.x, l2.y, l3.x, l3.y);
        __syncthreads();

        if (k0 + 32 < K) {   // prefetch next tile (overlaps MFMA below)
            const unsigned short* ah2 = Abh + k0 + 32;
            const unsigned short* al2 = Abl + k0 + 32;
            const float* b2 = Bb + k0 + 32;
            pah0 = *(const uint4*)ah2;  pah1 = *(const uint4*)(ah2 + 8);
            pal0 = *(const uint4*)al2;  pal1 = *(const uint4*)(al2 + 8);
            pb0 = ((const float4*)b2)[0]; pb1 = ((const float4*)b2)[1];
            pb2 = ((const float4*)b2)[2]; pb3 = ((const float4*)b2)[3];
        }

        bf16x8 afh[4], afl[4];
#pragma unroll
        for (int mt = 0; mt < 4; ++mt) {
            const int rr = (wm * 64 + mt * 16 + ln) * 40 + quad * 8;
            afh[mt] = __builtin_bit_cast(bf16x8, *(const uint4*)&Ah[rr]);
            afl[mt] = __builtin_bit_cast(bf16x8, *(const uint4*)&Al[rr]);
        }
#pragma unroll
        for (int nt = 0; nt < 4; ++nt) {
            const int rr = (wn * 64 + nt * 16 + ln) * 40 + quad * 8;
            bf16x8 bfh = __builtin_bit_cast(bf16x8, *(const uint4*)&Bh[rr]);
            bf16x8 bfl = __builtin_bit_cast(bf16x8, *(const uint4*)&Bl[rr]);
#pragma unroll
            for (int mt = 0; mt < 4; ++mt) {
                acc[mt][nt] = __builtin_amdgcn_mfma_f32_16x16x32_bf16(afh[mt], bfh, acc[mt][nt], 0, 0, 0);
                acc[mt][nt] = __builtin_amdgcn_mfma_f32_16x16x32_bf16(afl[mt], bfh, acc[mt][nt], 0, 0, 0);
                acc[mt][nt] = __builtin_amdgcn_mfma_f32_16x16x32_bf16(afh[mt], bfl, acc[mt][nt], 0, 0, 0);
            }
        }
    }

    float bias4[4];
#pragma unroll
    for (int nt = 0; nt < 4; ++nt) bias4[nt] = bias[n0 + wn * 64 + nt * 16 + ln];

    if (mode == 0) {
#pragma unroll
        for (int mt = 0; mt < 4; ++mt) {
            const int rbase = m0 + wm * 64 + mt * 16 + quad * 4;
#pragma unroll
            for (int reg = 0; reg < 4; ++reg) {
                float* cp = C + (size_t)(rbase + reg) * Nc + n0 + wn * 64 + ln;
#pragma unroll
                for (int nt = 0; nt < 4; ++nt)
                    cp[nt * 16] = acc[mt][nt][reg] + bias4[nt];
            }
        }
    } else {
        const int part = n0 / DXC;
        unsigned short* dst = (part == 0) ? qp : (part == 1) ? kp : vp;
        const int cc = (n0 % DXC) + wn * 64 + ln;
#pragma unroll
        for (int mt = 0; mt < 4; ++mt) {
            const int rbase = row_off + m0 + wm * 64 + mt * 16 + quad * 4;
#pragma unroll
            for (int reg = 0; reg < 4; ++reg) {
                unsigned short* cp = dst + (size_t)(rbase + reg) * DXC + cc;
#pragma unroll
                for (int nt = 0; nt < 4; ++nt)
                    cp[nt * 16] = f2bf(acc[mt][nt][reg] + bias4[nt]);
            }
        }
    }
}

// ---------------- per-head rmsnorm (+ rope for x tokens) on bf16 q/k ----------------
__global__ __launch_bounds__(128) void qknorm_rope_kernel(
    unsigned short* __restrict__ qb, unsigned short* __restrict__ kb,
    const float* __restrict__ qnx, const float* __restrict__ knx,
    const float* __restrict__ qny, const float* __restrict__ kny,
    const float* __restrict__ cosp, const float* __restrict__ sinp)
{
    const int bx = blockIdx.x;
    const int which = bx & 1;
    const int h = (bx >> 1) % NH;
    const int t = bx / (2 * NH);
    unsigned short* p = (which ? kb : qb) + (size_t)t * DXC + h * DH;
    const int d = threadIdx.x;
    const float v = bf2f(p[d]);
    float ss = v * v;
#pragma unroll
    for (int m = 1; m < 64; m <<= 1) ss += __shfl_xor(ss, m, 64);
    __shared__ float red[2];
    if ((d & 63) == 0) red[d >> 6] = ss;
    __syncthreads();
    const float tot = red[0] + red[1];
    const float r = rsqrtf(tot * (1.f / 128.f) + RMS_EPS);
    const float* w = (t < NX) ? (which ? knx : qnx) : (which ? kny : qny);
    const float nv = v * r * w[d];
    float outv = nv;
    if (t < NX) {
        const int pidx = d >> 1;
        const float cs = cosp[((size_t)t * NH + h) * 64 + pidx];
        const float sn = sinp[((size_t)t * NH + h) * 64 + pidx];
        const float partner = __shfl_xor(nv, 1, 64);
        outv = ((d & 1) == 0) ? (nv * cs - partner * sn)
                              : (partner * sn + nv * cs);
    }
    p[d] = f2bf(outv);
}

// ---------------- flash attention, bf16 MFMA 16x16x32 ----------------
#define BQ 64
#define BKV 64
#define NQT ((NTOT + BQ - 1) / BQ)   // 36
#define ATTN_SCALE 0.08838834764831845f

__global__ __launch_bounds__(256) void attn_kernel(
    const unsigned short* __restrict__ qb, const unsigned short* __restrict__ kb,
    const unsigned short* __restrict__ vb,
    unsigned short* __restrict__ out_hi, unsigned short* __restrict__ out_lo,
    const int* __restrict__ idx)
{
    __shared__ unsigned short Qs[64 * 136];
    __shared__ unsigned short Ks[64 * 136];
    __shared__ unsigned int   Vt[128 * 36];
    __shared__ unsigned short Ps[4][16 * 72];

    const int h  = blockIdx.x / NQT;
    const int qt = blockIdx.x % NQT;
    const int q0 = qt * BQ;
    const int tid  = threadIdx.x;
    const int wave = tid >> 6;
    const int lane = tid & 63;
    const int quad = lane >> 4;
    const int ln   = lane & 15;

    for (int c = tid; c < 64 * 16; c += 256) {
        const int row = c >> 4, ch = c & 15;
        const int qi = q0 + row;
        uint4 v = make_uint4(0, 0, 0, 0);
        if (qi < NTOT) {
            const int tok = idx[qi];
            v = *(const uint4*)(qb + (size_t)tok * DXC + h * DH + ch * 8);
        }
        *(uint4*)&Qs[row * 136 + ch * 8] = v;
    }
    __syncthreads();

    bf16x8 aq[4];
#pragma unroll
    for (int c = 0; c < 4; ++c)
        aq[c] = __builtin_bit_cast(bf16x8,
            *(const uint4*)&Qs[(wave * 16 + ln) * 136 + c * 32 + quad * 8]);

    f32x4 o[8];
#pragma unroll
    for (int dt = 0; dt < 8; ++dt) o[dt] = (f32x4){0.f, 0.f, 0.f, 0.f};
    float m_i[4] = {-1e30f, -1e30f, -1e30f, -1e30f};
    float l_i[4] = {0.f, 0.f, 0.f, 0.f};

    for (int kv0 = 0; kv0 < NTOT; kv0 += BKV) {
        __syncthreads();
        for (int c = tid; c < 64 * 16; c += 256) {
            const int row = c >> 4, ch = c & 15;
            const int ki = kv0 + row;
            uint4 v = make_uint4(0, 0, 0, 0);
            if (ki < NTOT)
                v = *(const uint4*)(kb + (size_t)idx[ki] * DXC + h * DH + ch * 8);
            *(uint4*)&Ks[row * 136 + ch * 8] = v;
        }
#pragma unroll
        for (int it = 0; it < 2; ++it) {
            const int pr = (tid >> 4) + it * 16;
            const int ch = tid & 15;
            const int k0i = kv0 + pr * 2, k1i = k0i + 1;
            uint4 a = make_uint4(0, 0, 0, 0), b = make_uint4(0, 0, 0, 0);
            if (k0i < NTOT)
                a = *(const uint4*)(vb + (size_t)idx[k0i] * DXC + h * DH + ch * 8);
            if (k1i < NTOT)
                b = *(const uint4*)(vb + (size_t)idx[k1i] * DXC + h * DH + ch * 8);
            unsigned int w[8];
            w[0] = (a.x & 0xffffu) | (b.x << 16);  w[1] = (a.x >> 16) | (b.x & 0xffff0000u);
            w[2] = (a.y & 0xffffu) | (b.y << 16);  w[3] = (a.y >> 16) | (b.y & 0xffff0000u);
            w[4] = (a.z & 0xffffu) | (b.z << 16);  w[5] = (a.z >> 16) | (b.z & 0xffff0000u);
            w[6] = (a.w & 0xffffu) | (b.w << 16);  w[7] = (a.w >> 16) | (b.w & 0xffff0000u);
#pragma unroll
            for (int s = 0; s < 8; ++s) {
                const int e = (s + ch) & 7;
                Vt[(ch * 8 + e) * 36 + pr] = w[e];
            }
        }
        __syncthreads();

        f32x4 sc[4];
#pragma unroll
        for (int t = 0; t < 4; ++t) {
            sc[t] = (f32x4){0.f, 0.f, 0.f, 0.f};
#pragma unroll
            for (int c = 0; c < 4; ++c) {
                bf16x8 bk = __builtin_bit_cast(bf16x8,
                    *(const uint4*)&Ks[(t * 16 + ln) * 136 + c * 32 + quad * 8]);
                sc[t] = __builtin_amdgcn_mfma_f32_16x16x32_bf16(aq[c], bk, sc[t], 0, 0, 0);
            }
        }

        float alpha[4];
#pragma unroll
        for (int r = 0; r < 4; ++r) {
            float mt = -1e30f;
#pragma unroll
            for (int t = 0; t < 4; ++t) {
                float sv = sc[t][r] * ATTN_SCALE;
                if (kv0 + t * 16 + ln >= NTOT) sv = -1e30f;
                sc[t][r] = sv;
                mt = fmaxf(mt, sv);
            }
#pragma unroll
            for (int mm = 1; mm < 16; mm <<= 1) mt = fmaxf(mt, __shfl_xor(mt, mm, 64));
            const float mn = fmaxf(m_i[r], mt);
            alpha[r] = __expf(m_i[r] - mn);
            m_i[r] = mn;
            float rs = 0.f;
#pragma unroll
            for (int t = 0; t < 4; ++t) {
                const float pv = __expf(sc[t][r] - mn);
                sc[t][r] = pv;
                rs += pv;
            }
#pragma unroll
            for (int mm = 1; mm < 16; mm <<= 1) rs += __shfl_xor(rs, mm, 64);
            l_i[r] = l_i[r] * alpha[r] + rs;
        }

        unsigned short* psw = Ps[wave];
#pragma unroll
        for (int t = 0; t < 4; ++t)
#pragma unroll
            for (int r = 0; r < 4; ++r)
                psw[(quad * 4 + r) * 72 + t * 16 + ln] = f2bf(sc[t][r]);

#pragma unroll
        for (int dt = 0; dt < 8; ++dt)
#pragma unroll
            for (int r = 0; r < 4; ++r) o[dt][r] *= alpha[r];

        bf16x8 ap0 = __builtin_bit_cast(bf16x8, *(const uint4*)&psw[ln * 72 + quad * 8]);
        bf16x8 ap1 = __builtin_bit_cast(bf16x8, *(const uint4*)&psw[ln * 72 + 32 + quad * 8]);
#pragma unroll
        for (int dt = 0; dt < 8; ++dt) {
            bf16x8 bv0 = __builtin_bit_cast(bf16x8,
                *(const uint4*)&Vt[(dt * 16 + ln) * 36 + quad * 4]);
            o[dt] = __builtin_amdgcn_mfma_f32_16x16x32_bf16(ap0, bv0, o[dt], 0, 0, 0);
            bf16x8 bv1 = __builtin_bit_cast(bf16x8,
                *(const uint4*)&Vt[(dt * 16 + ln) * 36 + 16 + quad * 4]);
            o[dt] = __builtin_amdgcn_mfma_f32_16x16x32_bf16(ap1, bv1, o[dt], 0, 0, 0);
        }
    }

#pragma unroll
    for (int r = 0; r < 4; ++r) {
        const int qrow = q0 + wave * 16 + quad * 4 + r;
        if (qrow >= NTOT) continue;
        const int tok = idx[qrow];
        const float inv = 1.f / l_i[r];
        unsigned short* hp = out_hi + (size_t)tok * DXC + h * DH + ln;
        unsigned short* lp = out_lo + (size_t)tok * DXC + h * DH + ln;
#pragma unroll
        for (int dt = 0; dt < 8; ++dt) {
            const float v = o[dt][r] * inv;
            const unsigned int u = __float_as_uint(v);
            hp[dt * 16] = (unsigned short)(u >> 16);
            lp[dt * 16] = f2bf(v - __uint_as_float(u & 0xffff0000u));
        }
    }
}

extern "C" void kernel_launch(void* const* d_in, const int* in_sizes, int n_in,
                              void* d_out, int out_size, void* d_ws, size_t ws_size,
                              hipStream_t stream)
{
    const float* x        = (const float*)d_in[0];
    const float* y        = (const float*)d_in[1];
    const float* scale_x  = (const float*)d_in[2];
    const float* scale_y  = (const float*)d_in[3];
    const float* rope_cos = (const float*)d_in[4];
    const float* rope_sin = (const float*)d_in[5];
    const float* W_qkv_x  = (const float*)d_in[6];
    const float* b_qkv_x  = (const float*)d_in[7];
    const float* W_qkv_y  = (const float*)d_in[8];
    const float* b_qkv_y  = (const float*)d_in[9];
    const float* q_norm_x = (const float*)d_in[10];
    const float* k_norm_x = (const float*)d_in[11];
    const float* q_norm_y = (const float*)d_in[12];
    const float* k_norm_y = (const float*)d_in[13];
    const float* W_proj_x = (const float*)d_in[14];
    const float* b_proj_x = (const float*)d_in[15];
    const float* W_proj_y = (const float*)d_in[16];
    const float* b_proj_y = (const float*)d_in[17];
    const int*   vidx     = (const int*)d_in[18];
    float* out = (float*)d_out;

    unsigned short* wsu = (unsigned short*)d_ws;
    const size_t SEG = (size_t)NLTOK * DXC;   // 7,077,888 elements
    unsigned short* q16     = wsu;
    unsigned short* k16     = wsu + SEG;
    unsigned short* v16     = wsu + 2 * SEG;
    unsigned short* attn_hi = wsu + 3 * SEG;
    unsigned short* attn_lo = wsu + 4 * SEG;
    unsigned short* xm_hi   = wsu + 5 * SEG;
    unsigned short* xm_lo   = wsu + 6 * SEG;
    unsigned short* ym_hi   = xm_hi + (size_t)NX * DXC;  // fits in SEG slack
    unsigned short* ym_lo   = xm_lo + (size_t)NX * DXC;

    // 0) zero attention scatter target (hi+lo contiguous)
    hipMemsetAsync(attn_hi, 0, 2 * SEG * sizeof(unsigned short), stream);

    // 1) rmsnorm * (1 + scale), pre-split hi/lo
    rmsnorm_scale_split_kernel<<<NX, 256, 0, stream>>>(x, scale_x, xm_hi, xm_lo, DXC);
    rmsnorm_scale_split_kernel<<<LY, 256, 0, stream>>>(y, scale_y, ym_hi, ym_lo, DYC);

    // 2) QKV GEMMs (split-bf16 3-term), scatter into bf16 q/k/v
    gemm_split_kernel<<<dim3(9216 / 128, NX / 128), 256, 0, stream>>>(
        xm_hi, xm_lo, W_qkv_x, b_qkv_x, nullptr, q16, k16, v16, 0, DXC, 1, 0);
    gemm_split_kernel<<<dim3(9216 / 128, LY / 128), 256, 0, stream>>>(
        ym_hi, ym_lo, W_qkv_y, b_qkv_y, nullptr, q16, k16, v16, 0, DYC, 1, NX);

    // 3) per-head q/k rmsnorm (+rope for x tokens)
    qknorm_rope_kernel<<<NLTOK * NH * 2, 128, 0, stream>>>(
        q16, k16, q_norm_x, k_norm_x, q_norm_y, k_norm_y, rope_cos, rope_sin);

    // 4) flash attention -> split hi/lo output
    attn_kernel<<<NH * NQT, 256, 0, stream>>>(q16, k16, v16, attn_hi, attn_lo, vidx);

    // 5) output projections (split-bf16 3-term)
    gemm_split_kernel<<<dim3(DXC / 128, NX / 128), 256, 0, stream>>>(
        attn_hi, attn_lo, W_proj_x, b_proj_x, out, nullptr, nullptr, nullptr,
        DXC, DXC, 0, 0);
    gemm_split_kernel<<<dim3(DYC / 128, LY / 128), 256, 0, stream>>>(
        attn_hi + (size_t)NX * DXC, attn_lo + (size_t)NX * DXC,
        W_proj_y, b_proj_y, out + (size_t)NX * DXC, nullptr, nullptr, nullptr,
        DYC, DXC, 0, 0);
}